// Round 7
// baseline (273.601 us; speedup 1.0000x reference)
//
#include <hip/hip_runtime.h>

#define NN   32
#define EMB  128
#define PEMB 64
#define ENCD 256
#define NLAY 4
#define W1C  261   // 2*EMB + 2*NCLS + 1
#define IND  193   // PEMB + 1 + EMB
#define UPAD 132   // padded row (floats): +16B breaks bank patterns

typedef __attribute__((ext_vector_type(8))) short short8;
typedef __attribute__((ext_vector_type(4))) float floatx4;

// ---- pre-converted weight fragments (bf16 hi/lo), filled by wconv kernel ----
__device__ unsigned short g_wC_h[16384 * 8], g_wC_l[16384 * 8];   // W1 frags
__device__ unsigned short g_wD_h[8192 * 8],  g_wD_l[8192 * 8];    // W2 frags
__device__ unsigned short g_wE1_h[16384 * 8], g_wE1_l[16384 * 8]; // UW1 frags
__device__ unsigned short g_wE2_h[8192 * 8],  g_wE2_l[8192 * 8];  // UW2 frags

// tanh(x) = 1 - 2/(exp(2x)+1)
__device__ __forceinline__ float fast_tanh(float x) {
  float e = __expf(2.0f * x);
  return 1.0f - __fdividef(2.0f, e + 1.0f);
}
// fp32 -> bf16 RNE
__device__ __forceinline__ unsigned short f2bf(float x) {
  unsigned u = __float_as_uint(x);
  return (unsigned short)((u + 0x7fffu + ((u >> 16) & 1u)) >> 16);
}
__device__ __forceinline__ float bf2f(unsigned short h) {
  return __uint_as_float(((unsigned)h) << 16);
}
// hw packed convert: dst.lo16 = bf16(a), dst.hi16 = bf16(b)
__device__ __forceinline__ unsigned cvtpk(float a, float b) {
  unsigned r;
  asm("v_cvt_pk_bf16_f32 %0, %1, %2" : "=v"(r) : "v"(a), "v"(b));
  return r;
}

// A*B with A,B split hi/lo bf16 (drop lo*lo): 3 MFMAs
__device__ __forceinline__ floatx4 mfma3(short8 ah, short8 al, short8 bh, short8 bl, floatx4 acc) {
  acc = __builtin_amdgcn_mfma_f32_16x16x32_bf16(ah, bh, acc, 0, 0, 0);
  acc = __builtin_amdgcn_mfma_f32_16x16x32_bf16(al, bh, acc, 0, 0, 0);
  acc = __builtin_amdgcn_mfma_f32_16x16x32_bf16(ah, bl, acc, 0, 0, 0);
  return acc;
}

// one fragment plane p (jt=p&1, kstep=p>>1) from fp32 [NN][UPAD] -> hi/lo frag LDS
__device__ __forceinline__ void cvt_plane(const float (*src)[UPAD],
                                          unsigned short (*dH)[64][8],
                                          unsigned short (*dL)[64][8],
                                          int p, int lane) {
  const int row  = (lane & 15) + ((p & 1) << 4);
  const int koff = ((p >> 1) << 5) + ((lane >> 4) << 3);
  float x[8];
  *(float4*)&x[0] = *(const float4*)&src[row][koff];
  *(float4*)&x[4] = *(const float4*)&src[row][koff + 4];
  unsigned h[4], lo[4];
  #pragma unroll
  for (int q = 0; q < 4; q++) {
    h[q] = cvtpk(x[2*q], x[2*q+1]);
    const float r0 = x[2*q]   - __uint_as_float(h[q] << 16);
    const float r1 = x[2*q+1] - __uint_as_float(h[q] & 0xffff0000u);
    lo[q] = cvtpk(r0, r1);
  }
  *(uint4*)&dH[p][lane][0] = make_uint4(h[0], h[1], h[2], h[3]);
  *(uint4*)&dL[p][lane][0] = make_uint4(lo[0], lo[1], lo[2], lo[3]);
}

// t-fragment build: tanh(u + v + d*c5) packed to bf16
__device__ __forceinline__ short8 build_t(const float* uv, const float* vv,
                                          float d, const float* c5q) {
  float t[8];
  #pragma unroll
  for (int m = 0; m < 8; m++) t[m] = fast_tanh(uv[m] + vv[m] + d * c5q[m]);
  uint4 p = make_uint4(cvtpk(t[0], t[1]), cvtpk(t[2], t[3]),
                       cvtpk(t[4], t[5]), cvtpk(t[6], t[7]));
  return *(short8*)&p;
}

__device__ __forceinline__ float dot16_lds(const float* base, const float* wreg) {
  const float4 a = *(const float4*)(base);
  const float4 b = *(const float4*)(base + 4);
  const float4 c = *(const float4*)(base + 8);
  const float4 d = *(const float4*)(base + 12);
  return a.x*wreg[0] + a.y*wreg[1] + a.z*wreg[2]  + a.w*wreg[3]
       + b.x*wreg[4] + b.y*wreg[5] + b.z*wreg[6]  + b.w*wreg[7]
       + c.x*wreg[8] + c.y*wreg[9] + c.z*wreg[10] + c.w*wreg[11]
       + d.x*wreg[12]+ d.y*wreg[13]+ d.z*wreg[14] + d.w*wreg[15];
}

// ---------------- weight pre-conversion: fp32 -> frag-ordered bf16 hi/lo ----------------
__global__ __launch_bounds__(256) void wconv(
    const float* __restrict__ msg_w1, const float* __restrict__ msg_w2,
    const float* __restrict__ upd_w1, const float* __restrict__ upd_w2) {
  const int t = blockIdx.x * 256 + threadIdx.x;
  const float* src;
  unsigned short *dh, *dl;
  if (t < 16384) {                               // W1 (Phase C): [l][tile][ks][lane][8]
    const int lane = t & 63, ks = (t >> 6) & 3, tile = (t >> 8) & 15, l = t >> 12;
    src = msg_w1 + l * EMB * W1C + (((tile & 7) << 4) + (lane & 15)) * W1C
        + (tile >> 3) * EMB + ks * 32 + ((lane >> 4) << 3);
    dh = g_wC_h + t * 8; dl = g_wC_l + t * 8;
  } else if (t < 24576) {                        // W2 (Phase D): [l][ct][ks][lane][8]
    const int r = t - 16384;
    const int lane = r & 63, ks = (r >> 6) & 3, ct = (r >> 8) & 7, l = r >> 11;
    src = msg_w2 + l * EMB * EMB + ((ct << 4) + (lane & 15)) * EMB + ks * 32 + ((lane >> 4) << 3);
    dh = g_wD_h + r * 8; dl = g_wD_l + r * 8;
  } else if (t < 40960) {                        // UW1 (E1): [l][ct][ks(8)][lane][8]
    const int r = t - 24576;
    const int lane = r & 63, ks = (r >> 6) & 7, ct = (r >> 9) & 7, l = r >> 12;
    src = upd_w1 + l * EMB * 2 * EMB + ((ct << 4) + (lane & 15)) * 2 * EMB + ks * 32 + ((lane >> 4) << 3);
    dh = g_wE1_h + r * 8; dl = g_wE1_l + r * 8;
  } else if (t < 49152) {                        // UW2 (E2): [l][ct][ks(4)][lane][8]
    const int r = t - 40960;
    const int lane = r & 63, ks = (r >> 6) & 3, ct = (r >> 8) & 7, l = r >> 11;
    src = upd_w2 + l * EMB * EMB + ((ct << 4) + (lane & 15)) * EMB + ks * 32 + ((lane >> 4) << 3);
    dh = g_wE2_h + r * 8; dl = g_wE2_l + r * 8;
  } else return;
  unsigned short hh[8], ll[8];
  #pragma unroll
  for (int m = 0; m < 8; m++) {
    const float x = src[m];
    const unsigned short hb = f2bf(x);
    hh[m] = hb;
    ll[m] = f2bf(x - bf2f(hb));
  }
  *(short8*)dh = *(const short8*)hh;
  *(short8*)dl = *(const short8*)ll;
}

__global__ __launch_bounds__(1024, 4) void fsd_fused(
    const float* __restrict__ pos, const float* __restrict__ enc,
    const float* __restrict__ pos_emb, const float* __restrict__ na_emb,
    const int* __restrict__ T,
    const float* __restrict__ fc1_w, const float* __restrict__ fc1_b,
    const float* __restrict__ fc2_w, const float* __restrict__ fc2_b,
    const float* __restrict__ lin_w, const float* __restrict__ lin_b,
    const float* __restrict__ msg_w1, const float* __restrict__ msg_b1,
    const float* __restrict__ msg_b2,
    const float* __restrict__ upd_b1, const float* __restrict__ upd_b2,
    float* __restrict__ out)
{
  __shared__ __align__(16) float h32[NN][UPAD];
  __shared__ __align__(16) float u_s[NN][UPAD];     // pos_emb staging; hid32 in E1
  __shared__ __align__(16) float v_s[NN][UPAD];
  __shared__ __align__(16) unsigned short hfH[8][64][8],  hfL[8][64][8];   // h A-frags
  __shared__ __align__(16) unsigned short agfH[8][64][8], agfL[8][64][8];  // aggr A-frags; hid frags in E2
  __shared__ __align__(16) unsigned short w2fH[8][4][64][8], w2fL[8][4][64][8]; // W2 B-frags (64 KB)
  __shared__ float e_s[EMB];
  __shared__ float c5_s[EMB];
  __shared__ float b2m_s[EMB];
  __shared__ float clsU[2][EMB], clsV[2][EMB];
  __shared__ float enc_s[ENCD];
  __shared__ float hidA_s[64];
  __shared__ float posx_s[NN], posy_s[NN];
  __shared__ int   T_s[NN];

  const int b    = blockIdx.x;
  const int tid  = threadIdx.x;
  const int w    = tid >> 6, lane = tid & 63;   // 16 waves
  const int o    = tid & 127, g8 = tid >> 7;    // [0,8): node-group for VALU phases
  const int l15  = lane & 15, l4 = lane >> 4;

  // ---------------- Phase A: decoder_fc -> e_s ----------------
  if (tid < ENCD) enc_s[tid] = enc[b * ENCD + tid];
  if (tid < NN) {
    posx_s[tid] = pos[(b * NN + tid) * 2 + 0];
    posy_s[tid] = pos[(b * NN + tid) * 2 + 1];
    T_s[tid]    = T[b * NN + tid];
  }
  __syncthreads();
  if (tid < 64) {
    float a = fc1_b[tid];
    const float* wr = fc1_w + tid * ENCD;
    #pragma unroll 8
    for (int k = 0; k < ENCD; k++) a += enc_s[k] * wr[k];
    hidA_s[tid] = fast_tanh(a);
  }
  __syncthreads();
  if (tid < EMB) {
    float a = fc2_b[tid];
    const float* wr = fc2_w + tid * 64;
    #pragma unroll 8
    for (int k = 0; k < 64; k++) a += hidA_s[k] * wr[k];
    e_s[tid] = a;
  }
  float* pe_s = &u_s[0][0];
  for (int idx = tid; idx < NN * PEMB; idx += 1024)
    pe_s[idx] = pos_emb[b * NN * PEMB + idx];
  __syncthreads();

  // ---------------- Phase B: h0 = x @ lin_w^T + lin_b ----------------
  {
    const float nav = na_emb[b];
    const float* wr = lin_w + o * IND;
    float ebias = lin_b[o] + nav * wr[PEMB];
    #pragma unroll 8
    for (int k = 0; k < EMB; k++) ebias += e_s[k] * wr[65 + k];
    float acc[4];
    #pragma unroll
    for (int n = 0; n < 4; n++) acc[n] = ebias;
    for (int kc = 0; kc < PEMB; kc += 16) {
      float wreg[16];
      #pragma unroll
      for (int q = 0; q < 16; q++) wreg[q] = wr[kc + q];
      #pragma unroll
      for (int n = 0; n < 4; n++)
        acc[n] += dot16_lds(&pe_s[(g8 + 8 * n) * PEMB + kc], wreg);
    }
    __syncthreads();   // pe reads done before u_s reuse
    #pragma unroll
    for (int n = 0; n < 4; n++) h32[g8 + 8 * n][o] = acc[n];
  }
  __syncthreads();
  if (w < 8) cvt_plane(h32, hfH, hfL, w, lane);
  __syncthreads();

  // ---------------- Layer loop ----------------
  for (int l = 0; l < NLAY; l++) {
    const float* b1  = msg_b1 + l * EMB;
    const float* b2  = msg_b2 + l * EMB;
    const float* ub1 = upd_b1 + l * EMB;
    const float* ub2 = upd_b2 + l * EMB;
    const float* w1  = msg_w1 + l * EMB * W1C;   // c5/cls columns only

    // ---- stage: c5, b2, cls tables; W2 frags -> LDS ----
    if (tid < EMB) { c5_s[tid] = w1[tid * W1C + 260]; b2m_s[tid] = b2[tid]; }
    {
      const int c = (tid >> 7) & 1, oo = tid & 127;
      if (tid < 256)      clsU[c][oo] = b1[oo] + w1[oo * W1C + 258 + c];
      else if (tid < 512) clsV[c][oo] = w1[oo * W1C + 256 + c];
    }
    {
      const unsigned short* sH = g_wD_h + l * 16384;
      const unsigned short* sL = g_wD_l + l * 16384;
      unsigned short* dH = &w2fH[0][0][0][0];
      unsigned short* dL = &w2fL[0][0][0][0];
      for (int idx = tid; idx < 2048; idx += 1024) {
        *(short8*)(dH + idx * 8) = *(const short8*)(sH + idx * 8);
        *(short8*)(dL + idx * 8) = *(const short8*)(sL + idx * 8);
      }
    }
    __syncthreads();   // (1) tables + w2f ready, h-frags ready

    // ---- Phase C: u,v = h @ W1parts^T via MFMA; wave w owns col-tile w of 16 ----
    {
      const int part = w >> 3;                   // 0 -> u, 1 -> v
      const int col  = ((w & 7) << 4) + l15;
      floatx4 acc0 = {0.f,0.f,0.f,0.f}, acc1 = {0.f,0.f,0.f,0.f};
      #pragma unroll
      for (int ks = 0; ks < 4; ks++) {
        const int idx = (((l * 16 + w) * 4 + ks) * 64 + lane) * 8;
        const short8 bh = *(const short8*)(g_wC_h + idx);
        const short8 bl = *(const short8*)(g_wC_l + idx);
        const short8 ah0 = *(const short8*)&hfH[ks*2+0][lane][0];
        const short8 al0 = *(const short8*)&hfL[ks*2+0][lane][0];
        const short8 ah1 = *(const short8*)&hfH[ks*2+1][lane][0];
        const short8 al1 = *(const short8*)&hfL[ks*2+1][lane][0];
        acc0 = mfma3(ah0, al0, bh, bl, acc0);
        acc1 = mfma3(ah1, al1, bh, bl, acc1);
      }
      float (*dst)[UPAD] = part ? v_s : u_s;
      const float (*tab)[EMB] = part ? clsV : clsU;
      #pragma unroll
      for (int q = 0; q < 4; q++) {
        const int r0 = (l4 << 2) + q;
        const int r1 = r0 + 16;
        dst[r0][col] = acc0[q] + tab[T_s[r0]][col];
        dst[r1][col] = acc1[q] + tab[T_s[r1]][col];
      }
    }
    __syncthreads();   // (2) u,v ready

    // ---- Phase D: wave-independent. Wave w owns dst nodes i0=2w, i1=2w+1.
    //      A-frags for BOTH nodes in registers; W2 B-frags read once per ct. ----
    {
      const int i0 = (w << 1), i1 = i0 + 1;
      const int j0 = l15, j1 = l15 + 16;
      const float pj0x = posx_s[j0], pj0y = posy_s[j0];
      const float pj1x = posx_s[j1], pj1y = posy_s[j1];
      const float pi0x = posx_s[i0], pi0y = posy_s[i0];
      const float pi1x = posx_s[i1], pi1y = posy_s[i1];
      float dx, dy;
      dx = pj0x - pi0x; dy = pj0y - pi0y; const float d00 = sqrtf(dx*dx + dy*dy);
      dx = pj1x - pi0x; dy = pj1y - pi0y; const float d01 = sqrtf(dx*dx + dy*dy);
      dx = pj0x - pi1x; dy = pj0y - pi1y; const float d10 = sqrtf(dx*dx + dy*dy);
      dx = pj1x - pi1x; dy = pj1y - pi1y; const float d11 = sqrtf(dx*dx + dy*dy);

      short8 aF0[8], aF1[8];
      #pragma unroll
      for (int q = 0; q < 4; q++) {              // k-range q*32 + l4*8
        const int k8 = (q << 5) + (l4 << 3);
        float v0[8], v1[8], c5q[8], uv0[8], uv1[8];
        *(float4*)&v0[0]  = *(const float4*)&v_s[j0][k8];
        *(float4*)&v0[4]  = *(const float4*)&v_s[j0][k8 + 4];
        *(float4*)&v1[0]  = *(const float4*)&v_s[j1][k8];
        *(float4*)&v1[4]  = *(const float4*)&v_s[j1][k8 + 4];
        *(float4*)&c5q[0] = *(const float4*)&c5_s[k8];
        *(float4*)&c5q[4] = *(const float4*)&c5_s[k8 + 4];
        *(float4*)&uv0[0] = *(const float4*)&u_s[i0][k8];
        *(float4*)&uv0[4] = *(const float4*)&u_s[i0][k8 + 4];
        *(float4*)&uv1[0] = *(const float4*)&u_s[i1][k8];
        *(float4*)&uv1[4] = *(const float4*)&u_s[i1][k8 + 4];
        aF0[2*q]     = build_t(uv0, v0, d00, c5q);
        aF0[2*q + 1] = build_t(uv0, v1, d01, c5q);
        aF1[2*q]     = build_t(uv1, v0, d10, c5q);
        aF1[2*q + 1] = build_t(uv1, v1, d11, c5q);
      }

      #pragma unroll
      for (int ct = 0; ct < 8; ct++) {
        floatx4 a00 = {0.f,0.f,0.f,0.f}, a01 = {0.f,0.f,0.f,0.f};
        floatx4 a10 = {0.f,0.f,0.f,0.f}, a11 = {0.f,0.f,0.f,0.f};
        #pragma unroll
        for (int ks = 0; ks < 4; ks++) {
          const short8 bh = *(const short8*)&w2fH[ct][ks][lane][0];
          const short8 bl = *(const short8*)&w2fL[ct][ks][lane][0];
          a00 = __builtin_amdgcn_mfma_f32_16x16x32_bf16(aF0[2*ks],   bl, a00, 0, 0, 0);
          a00 = __builtin_amdgcn_mfma_f32_16x16x32_bf16(aF0[2*ks],   bh, a00, 0, 0, 0);
          a01 = __builtin_amdgcn_mfma_f32_16x16x32_bf16(aF0[2*ks+1], bl, a01, 0, 0, 0);
          a01 = __builtin_amdgcn_mfma_f32_16x16x32_bf16(aF0[2*ks+1], bh, a01, 0, 0, 0);
          a10 = __builtin_amdgcn_mfma_f32_16x16x32_bf16(aF1[2*ks],   bl, a10, 0, 0, 0);
          a10 = __builtin_amdgcn_mfma_f32_16x16x32_bf16(aF1[2*ks],   bh, a10, 0, 0, 0);
          a11 = __builtin_amdgcn_mfma_f32_16x16x32_bf16(aF1[2*ks+1], bl, a11, 0, 0, 0);
          a11 = __builtin_amdgcn_mfma_f32_16x16x32_bf16(aF1[2*ks+1], bh, a11, 0, 0, 0);
        }
        const float b2c = b2m_s[(ct << 4) + l15];
        const int c     = (ct << 4) + l15;
        const int sl_hi = ((c >> 3) & 3) << 4;
        const int elem  = c & 7;
        float p0 = 0.f, p1 = 0.f;
        #pragma unroll
        for (int q = 0; q < 4; q++) {
          p0 += fast_tanh(a00[q] + b2c) + fast_tanh(a01[q] + b2c);
          p1 += fast_tanh(a10[q] + b2c) + fast_tanh(a11[q] + b2c);
        }
        p0 += __shfl_xor(p0, 16); p0 += __shfl_xor(p0, 32);
        p1 += __shfl_xor(p1, 16); p1 += __shfl_xor(p1, 32);
        if (lane < 16) {
          const int plane0 = ((c >> 5) << 1) + (i0 >> 4);
          const int plane1 = ((c >> 5) << 1) + (i1 >> 4);
          unsigned short hb;
          hb = f2bf(p0);
          agfH[plane0][(i0 & 15) + sl_hi][elem] = hb;
          agfL[plane0][(i0 & 15) + sl_hi][elem] = f2bf(p0 - bf2f(hb));
          hb = f2bf(p1);
          agfH[plane1][(i1 & 15) + sl_hi][elem] = hb;
          agfL[plane1][(i1 & 15) + sl_hi][elem] = f2bf(p1 - bf2f(hb));
        }
      }
    }
    __syncthreads();   // (3) agf complete; u_s free

    // ---- Phase E1: hid = tanh([h|aggr] @ uw1^T + ub1) -> u_s.
    //      wave w: col-tile ct = w&7, row-half jt = w>>3 ----
    {
      const int ct = w & 7, jt = w >> 3;
      const int col = (ct << 4) + l15;
      const float bo = ub1[col];
      floatx4 acc = {0.f,0.f,0.f,0.f};
      #pragma unroll
      for (int ks = 0; ks < 8; ks++) {
        const int idx = (((l * 8 + ct) * 8 + ks) * 64 + lane) * 8;
        const short8 bh = *(const short8*)(g_wE1_h + idx);
        const short8 bl = *(const short8*)(g_wE1_l + idx);
        short8 ah, al;
        if (ks < 4) {
          ah = *(const short8*)&hfH[ks*2+jt][lane][0];
          al = *(const short8*)&hfL[ks*2+jt][lane][0];
        } else {
          ah = *(const short8*)&agfH[(ks-4)*2+jt][lane][0];
          al = *(const short8*)&agfL[(ks-4)*2+jt][lane][0];
        }
        acc = mfma3(ah, al, bh, bl, acc);
      }
      __syncthreads();   // (4) agf/hf reads done before agf reuse as hid frags
      #pragma unroll
      for (int q = 0; q < 4; q++) {
        const int r = (jt << 4) + (l4 << 2) + q;
        u_s[r][col] = fast_tanh(acc[q] + bo);    // u_s reused as hid32
      }
    }
    __syncthreads();   // (5) hid32 ready

    if (w < 8) cvt_plane(u_s, agfH, agfL, w, lane);   // hid frags into agf
    __syncthreads();   // (6)

    // ---- Phase E2: h += tanh(hid @ uw2^T + ub2); same (ct, jt) split ----
    {
      const int ct = w & 7, jt = w >> 3;
      const int col = (ct << 4) + l15;
      const float bo = ub2[col];
      floatx4 acc = {0.f,0.f,0.f,0.f};
      #pragma unroll
      for (int ks = 0; ks < 4; ks++) {
        const int idx = (((l * 8 + ct) * 4 + ks) * 64 + lane) * 8;
        const short8 bh = *(const short8*)(g_wE2_h + idx);
        const short8 bl = *(const short8*)(g_wE2_l + idx);
        const short8 ah = *(const short8*)&agfH[ks*2+jt][lane][0];
        const short8 al = *(const short8*)&agfL[ks*2+jt][lane][0];
        acc = mfma3(ah, al, bh, bl, acc);
      }
      #pragma unroll
      for (int q = 0; q < 4; q++) {
        const int r = (jt << 4) + (l4 << 2) + q;
        h32[r][col] += fast_tanh(acc[q] + bo);
      }
    }
    __syncthreads();   // (7) h updated

    if (l + 1 < NLAY) {
      if (w < 8) cvt_plane(h32, hfH, hfL, w, lane);
      __syncthreads();
    }
  }

  // ---------------- write out ----------------
  for (int idx = tid; idx < NN * EMB; idx += 1024)
    out[b * NN * EMB + idx] = h32[idx >> 7][idx & 127];
}

extern "C" void kernel_launch(void* const* d_in, const int* in_sizes, int n_in,
                              void* d_out, int out_size, void* d_ws, size_t ws_size,
                              hipStream_t stream) {
  const float* pos     = (const float*)d_in[0];
  const float* enc     = (const float*)d_in[1];
  const float* pos_emb = (const float*)d_in[2];
  const float* na_emb  = (const float*)d_in[3];
  const int*   T       = (const int*)d_in[4];
  // d_in[5] = num_agents (compile-time 32)
  const float* fc1_w = (const float*)d_in[6];
  const float* fc1_b = (const float*)d_in[7];
  const float* fc2_w = (const float*)d_in[8];
  const float* fc2_b = (const float*)d_in[9];
  const float* lin_w = (const float*)d_in[10];
  const float* lin_b = (const float*)d_in[11];
  const float* msg_w1 = (const float*)d_in[12];
  const float* msg_b1 = (const float*)d_in[13];
  const float* msg_w2 = (const float*)d_in[14];
  const float* msg_b2 = (const float*)d_in[15];
  const float* upd_w1 = (const float*)d_in[16];
  const float* upd_b1 = (const float*)d_in[17];
  const float* upd_w2 = (const float*)d_in[18];
  const float* upd_b2 = (const float*)d_in[19];

  wconv<<<192, 256, 0, stream>>>(msg_w1, msg_w2, upd_w1, upd_w2);
  fsd_fused<<<256, 1024, 0, stream>>>(pos, enc, pos_emb, na_emb, T,
      fc1_w, fc1_b, fc2_w, fc2_b, lin_w, lin_b,
      msg_w1, msg_b1, msg_b2, upd_b1, upd_b2,
      (float*)d_out);
}

// Round 8
// 251.752 us; speedup vs baseline: 1.0868x; 1.0868x over previous
//
#include <hip/hip_runtime.h>

#define NN   32
#define EMB  128
#define PEMB 64
#define ENCD 256
#define NLAY 4
#define W1C  261   // 2*EMB + 2*NCLS + 1
#define IND  193   // PEMB + 1 + EMB
#define UPAD 132   // padded row (floats): +16B breaks bank patterns

typedef __attribute__((ext_vector_type(8))) short short8;
typedef __attribute__((ext_vector_type(4))) float floatx4;

// ---- pre-converted weight fragments (bf16 hi/lo), filled by wconv kernel ----
__device__ unsigned short g_wC_h[16384 * 8], g_wC_l[16384 * 8];   // W1 frags
__device__ unsigned short g_wD_h[8192 * 8],  g_wD_l[8192 * 8];    // W2 frags
__device__ unsigned short g_wE1_h[16384 * 8], g_wE1_l[16384 * 8]; // UW1 frags
__device__ unsigned short g_wE2_h[8192 * 8],  g_wE2_l[8192 * 8];  // UW2 frags

// tanh(x) = 1 - 2/(exp(2x)+1)
__device__ __forceinline__ float fast_tanh(float x) {
  float e = __expf(2.0f * x);
  return 1.0f - __fdividef(2.0f, e + 1.0f);
}
// fp32 -> bf16 RNE
__device__ __forceinline__ unsigned short f2bf(float x) {
  unsigned u = __float_as_uint(x);
  return (unsigned short)((u + 0x7fffu + ((u >> 16) & 1u)) >> 16);
}
__device__ __forceinline__ float bf2f(unsigned short h) {
  return __uint_as_float(((unsigned)h) << 16);
}
// hw packed convert: dst.lo16 = bf16(a), dst.hi16 = bf16(b)
__device__ __forceinline__ unsigned cvtpk(float a, float b) {
  unsigned r;
  asm("v_cvt_pk_bf16_f32 %0, %1, %2" : "=v"(r) : "v"(a), "v"(b));
  return r;
}

// A*B with A,B split hi/lo bf16 (drop lo*lo): 3 MFMAs
__device__ __forceinline__ floatx4 mfma3(short8 ah, short8 al, short8 bh, short8 bl, floatx4 acc) {
  acc = __builtin_amdgcn_mfma_f32_16x16x32_bf16(ah, bh, acc, 0, 0, 0);
  acc = __builtin_amdgcn_mfma_f32_16x16x32_bf16(al, bh, acc, 0, 0, 0);
  acc = __builtin_amdgcn_mfma_f32_16x16x32_bf16(ah, bl, acc, 0, 0, 0);
  return acc;
}

// one fragment plane p (jt=p&1, kstep=p>>1) from fp32 [NN][UPAD] -> hi/lo frag LDS
__device__ __forceinline__ void cvt_plane(const float (*src)[UPAD],
                                          unsigned short (*dH)[64][8],
                                          unsigned short (*dL)[64][8],
                                          int p, int lane) {
  const int row  = (lane & 15) + ((p & 1) << 4);
  const int koff = ((p >> 1) << 5) + ((lane >> 4) << 3);
  float x[8];
  *(float4*)&x[0] = *(const float4*)&src[row][koff];
  *(float4*)&x[4] = *(const float4*)&src[row][koff + 4];
  unsigned h[4], lo[4];
  #pragma unroll
  for (int q = 0; q < 4; q++) {
    h[q] = cvtpk(x[2*q], x[2*q+1]);
    const float r0 = x[2*q]   - __uint_as_float(h[q] << 16);
    const float r1 = x[2*q+1] - __uint_as_float(h[q] & 0xffff0000u);
    lo[q] = cvtpk(r0, r1);
  }
  *(uint4*)&dH[p][lane][0] = make_uint4(h[0], h[1], h[2], h[3]);
  *(uint4*)&dL[p][lane][0] = make_uint4(lo[0], lo[1], lo[2], lo[3]);
}

// t-fragment build: tanh(u + v + d*c5) packed to bf16
__device__ __forceinline__ short8 build_t(const float* uv, const float* vv,
                                          float d, const float* c5q) {
  float t[8];
  #pragma unroll
  for (int m = 0; m < 8; m++) t[m] = fast_tanh(uv[m] + vv[m] + d * c5q[m]);
  uint4 p = make_uint4(cvtpk(t[0], t[1]), cvtpk(t[2], t[3]),
                       cvtpk(t[4], t[5]), cvtpk(t[6], t[7]));
  return *(short8*)&p;
}

__device__ __forceinline__ float dot16_lds(const float* base, const float* wreg) {
  const float4 a = *(const float4*)(base);
  const float4 b = *(const float4*)(base + 4);
  const float4 c = *(const float4*)(base + 8);
  const float4 d = *(const float4*)(base + 12);
  return a.x*wreg[0] + a.y*wreg[1] + a.z*wreg[2]  + a.w*wreg[3]
       + b.x*wreg[4] + b.y*wreg[5] + b.z*wreg[6]  + b.w*wreg[7]
       + c.x*wreg[8] + c.y*wreg[9] + c.z*wreg[10] + c.w*wreg[11]
       + d.x*wreg[12]+ d.y*wreg[13]+ d.z*wreg[14] + d.w*wreg[15];
}

// ---------------- weight pre-conversion: fp32 -> frag-ordered bf16 hi/lo ----------------
__global__ __launch_bounds__(256) void wconv(
    const float* __restrict__ msg_w1, const float* __restrict__ msg_w2,
    const float* __restrict__ upd_w1, const float* __restrict__ upd_w2) {
  const int t = blockIdx.x * 256 + threadIdx.x;
  const float* src;
  unsigned short *dh, *dl;
  if (t < 16384) {                               // W1 (Phase C): [l][tile][ks][lane][8]
    const int lane = t & 63, ks = (t >> 6) & 3, tile = (t >> 8) & 15, l = t >> 12;
    src = msg_w1 + l * EMB * W1C + (((tile & 7) << 4) + (lane & 15)) * W1C
        + (tile >> 3) * EMB + ks * 32 + ((lane >> 4) << 3);
    dh = g_wC_h + t * 8; dl = g_wC_l + t * 8;
  } else if (t < 24576) {                        // W2 (Phase D): [l][ct][ks][lane][8]
    const int r = t - 16384;
    const int lane = r & 63, ks = (r >> 6) & 3, ct = (r >> 8) & 7, l = r >> 11;
    src = msg_w2 + l * EMB * EMB + ((ct << 4) + (lane & 15)) * EMB + ks * 32 + ((lane >> 4) << 3);
    dh = g_wD_h + r * 8; dl = g_wD_l + r * 8;
  } else if (t < 40960) {                        // UW1 (E1): [l][ct][ks(8)][lane][8]
    const int r = t - 24576;
    const int lane = r & 63, ks = (r >> 6) & 7, ct = (r >> 9) & 7, l = r >> 12;
    src = upd_w1 + l * EMB * 2 * EMB + ((ct << 4) + (lane & 15)) * 2 * EMB + ks * 32 + ((lane >> 4) << 3);
    dh = g_wE1_h + r * 8; dl = g_wE1_l + r * 8;
  } else if (t < 49152) {                        // UW2 (E2): [l][ct][ks(4)][lane][8]
    const int r = t - 40960;
    const int lane = r & 63, ks = (r >> 6) & 3, ct = (r >> 8) & 7, l = r >> 11;
    src = upd_w2 + l * EMB * EMB + ((ct << 4) + (lane & 15)) * EMB + ks * 32 + ((lane >> 4) << 3);
    dh = g_wE2_h + r * 8; dl = g_wE2_l + r * 8;
  } else return;
  unsigned short hh[8], ll[8];
  #pragma unroll
  for (int m = 0; m < 8; m++) {
    const float x = src[m];
    const unsigned short hb = f2bf(x);
    hh[m] = hb;
    ll[m] = f2bf(x - bf2f(hb));
  }
  *(short8*)dh = *(const short8*)hh;
  *(short8*)dl = *(const short8*)ll;
}

__global__ __launch_bounds__(1024)
__attribute__((amdgpu_waves_per_eu(4, 4)))     // exactly 4 waves/EU: VGPR budget 128, no 8-wave spill chase
void fsd_fused(
    const float* __restrict__ pos, const float* __restrict__ enc,
    const float* __restrict__ pos_emb, const float* __restrict__ na_emb,
    const int* __restrict__ T,
    const float* __restrict__ fc1_w, const float* __restrict__ fc1_b,
    const float* __restrict__ fc2_w, const float* __restrict__ fc2_b,
    const float* __restrict__ lin_w, const float* __restrict__ lin_b,
    const float* __restrict__ msg_w1, const float* __restrict__ msg_b1,
    const float* __restrict__ msg_b2,
    const float* __restrict__ upd_b1, const float* __restrict__ upd_b2,
    float* __restrict__ out)
{
  __shared__ __align__(16) float h32[NN][UPAD];
  __shared__ __align__(16) float u_s[NN][UPAD];     // pos_emb staging; hid32 in E1
  __shared__ __align__(16) float v_s[NN][UPAD];
  __shared__ __align__(16) unsigned short hfH[8][64][8],  hfL[8][64][8];   // h A-frags
  __shared__ __align__(16) unsigned short agfH[8][64][8], agfL[8][64][8];  // aggr A-frags; hid frags in E2
  __shared__ __align__(16) unsigned short w2fH[8][4][64][8], w2fL[8][4][64][8]; // W2 B-frags (64 KB)
  __shared__ float e_s[EMB];
  __shared__ float c5_s[EMB];
  __shared__ float b2m_s[EMB];
  __shared__ float clsU[2][EMB], clsV[2][EMB];
  __shared__ float enc_s[ENCD];
  __shared__ float hidA_s[64];
  __shared__ float posx_s[NN], posy_s[NN];
  __shared__ int   T_s[NN];

  const int b    = blockIdx.x;
  const int tid  = threadIdx.x;
  const int w    = tid >> 6, lane = tid & 63;   // 16 waves
  const int o    = tid & 127, g8 = tid >> 7;    // [0,8): node-group for VALU phases
  const int l15  = lane & 15, l4 = lane >> 4;

  // ---------------- Phase A: decoder_fc -> e_s ----------------
  if (tid < ENCD) enc_s[tid] = enc[b * ENCD + tid];
  if (tid < NN) {
    posx_s[tid] = pos[(b * NN + tid) * 2 + 0];
    posy_s[tid] = pos[(b * NN + tid) * 2 + 1];
    T_s[tid]    = T[b * NN + tid];
  }
  __syncthreads();
  if (tid < 64) {
    float a = fc1_b[tid];
    const float* wr = fc1_w + tid * ENCD;
    #pragma unroll 8
    for (int k = 0; k < ENCD; k++) a += enc_s[k] * wr[k];
    hidA_s[tid] = fast_tanh(a);
  }
  __syncthreads();
  if (tid < EMB) {
    float a = fc2_b[tid];
    const float* wr = fc2_w + tid * 64;
    #pragma unroll 8
    for (int k = 0; k < 64; k++) a += hidA_s[k] * wr[k];
    e_s[tid] = a;
  }
  float* pe_s = &u_s[0][0];
  for (int idx = tid; idx < NN * PEMB; idx += 1024)
    pe_s[idx] = pos_emb[b * NN * PEMB + idx];
  __syncthreads();

  // ---------------- Phase B: h0 = x @ lin_w^T + lin_b ----------------
  {
    const float nav = na_emb[b];
    const float* wr = lin_w + o * IND;
    float ebias = lin_b[o] + nav * wr[PEMB];
    #pragma unroll 8
    for (int k = 0; k < EMB; k++) ebias += e_s[k] * wr[65 + k];
    float acc[4];
    #pragma unroll
    for (int n = 0; n < 4; n++) acc[n] = ebias;
    for (int kc = 0; kc < PEMB; kc += 16) {
      float wreg[16];
      #pragma unroll
      for (int q = 0; q < 16; q++) wreg[q] = wr[kc + q];
      #pragma unroll
      for (int n = 0; n < 4; n++)
        acc[n] += dot16_lds(&pe_s[(g8 + 8 * n) * PEMB + kc], wreg);
    }
    __syncthreads();   // pe reads done before u_s reuse
    #pragma unroll
    for (int n = 0; n < 4; n++) h32[g8 + 8 * n][o] = acc[n];
  }
  __syncthreads();
  if (w < 8) cvt_plane(h32, hfH, hfL, w, lane);
  __syncthreads();

  // ---------------- Layer loop ----------------
  for (int l = 0; l < NLAY; l++) {
    const float* b1  = msg_b1 + l * EMB;
    const float* b2  = msg_b2 + l * EMB;
    const float* ub1 = upd_b1 + l * EMB;
    const float* ub2 = upd_b2 + l * EMB;
    const float* w1  = msg_w1 + l * EMB * W1C;   // c5/cls columns only

    // ---- stage: c5, b2, cls tables; W2 frags -> LDS ----
    if (tid < EMB) { c5_s[tid] = w1[tid * W1C + 260]; b2m_s[tid] = b2[tid]; }
    {
      const int c = (tid >> 7) & 1, oo = tid & 127;
      if (tid < 256)      clsU[c][oo] = b1[oo] + w1[oo * W1C + 258 + c];
      else if (tid < 512) clsV[c][oo] = w1[oo * W1C + 256 + c];
    }
    {
      const unsigned short* sH = g_wD_h + l * 16384;
      const unsigned short* sL = g_wD_l + l * 16384;
      unsigned short* dH = &w2fH[0][0][0][0];
      unsigned short* dL = &w2fL[0][0][0][0];
      for (int idx = tid; idx < 2048; idx += 1024) {
        *(short8*)(dH + idx * 8) = *(const short8*)(sH + idx * 8);
        *(short8*)(dL + idx * 8) = *(const short8*)(sL + idx * 8);
      }
    }
    __syncthreads();   // (1) tables + w2f ready, h-frags ready

    // ---- Phase C: u,v = h @ W1parts^T via MFMA; wave w owns col-tile w of 16 ----
    {
      const int part = w >> 3;                   // 0 -> u, 1 -> v
      const int col  = ((w & 7) << 4) + l15;
      floatx4 acc0 = {0.f,0.f,0.f,0.f}, acc1 = {0.f,0.f,0.f,0.f};
      #pragma unroll
      for (int ks = 0; ks < 4; ks++) {
        const int idx = (((l * 16 + w) * 4 + ks) * 64 + lane) * 8;
        const short8 bh = *(const short8*)(g_wC_h + idx);
        const short8 bl = *(const short8*)(g_wC_l + idx);
        const short8 ah0 = *(const short8*)&hfH[ks*2+0][lane][0];
        const short8 al0 = *(const short8*)&hfL[ks*2+0][lane][0];
        const short8 ah1 = *(const short8*)&hfH[ks*2+1][lane][0];
        const short8 al1 = *(const short8*)&hfL[ks*2+1][lane][0];
        acc0 = mfma3(ah0, al0, bh, bl, acc0);
        acc1 = mfma3(ah1, al1, bh, bl, acc1);
      }
      float (*dst)[UPAD] = part ? v_s : u_s;
      const float (*tab)[EMB] = part ? clsV : clsU;
      #pragma unroll
      for (int q = 0; q < 4; q++) {
        const int r0 = (l4 << 2) + q;
        const int r1 = r0 + 16;
        dst[r0][col] = acc0[q] + tab[T_s[r0]][col];
        dst[r1][col] = acc1[q] + tab[T_s[r1]][col];
      }
    }
    __syncthreads();   // (2) u,v ready

    // ---- Phase D: wave-independent. Wave w owns dst nodes 2w, 2w+1,
    //      processed SEQUENTIALLY (one aF[8] live -> no spill). ----
    {
      const int j0 = l15, j1 = l15 + 16;
      const float pj0x = posx_s[j0], pj0y = posy_s[j0];
      const float pj1x = posx_s[j1], pj1y = posy_s[j1];
      for (int ii = 0; ii < 2; ii++) {
        const int i = (w << 1) + ii;
        const float pix = posx_s[i], piy = posy_s[i];
        float dx0 = pj0x - pix, dy0 = pj0y - piy;
        float dx1 = pj1x - pix, dy1 = pj1y - piy;
        const float d0 = sqrtf(dx0 * dx0 + dy0 * dy0);
        const float d1 = sqrtf(dx1 * dx1 + dy1 * dy1);

        short8 aF[8];
        #pragma unroll
        for (int q = 0; q < 4; q++) {            // k-range q*32 + l4*8
          const int k8 = (q << 5) + (l4 << 3);
          float v0[8], v1[8], c5q[8], uv[8];
          *(float4*)&v0[0]  = *(const float4*)&v_s[j0][k8];
          *(float4*)&v0[4]  = *(const float4*)&v_s[j0][k8 + 4];
          *(float4*)&v1[0]  = *(const float4*)&v_s[j1][k8];
          *(float4*)&v1[4]  = *(const float4*)&v_s[j1][k8 + 4];
          *(float4*)&c5q[0] = *(const float4*)&c5_s[k8];
          *(float4*)&c5q[4] = *(const float4*)&c5_s[k8 + 4];
          *(float4*)&uv[0]  = *(const float4*)&u_s[i][k8];
          *(float4*)&uv[4]  = *(const float4*)&u_s[i][k8 + 4];
          aF[2*q]     = build_t(uv, v0, d0, c5q);
          aF[2*q + 1] = build_t(uv, v1, d1, c5q);
        }

        #pragma unroll
        for (int ct = 0; ct < 8; ct++) {
          floatx4 a0 = {0.f,0.f,0.f,0.f}, a1 = {0.f,0.f,0.f,0.f};
          #pragma unroll
          for (int ks = 0; ks < 4; ks++) {
            const short8 bh = *(const short8*)&w2fH[ct][ks][lane][0];
            const short8 bl = *(const short8*)&w2fL[ct][ks][lane][0];
            a0 = __builtin_amdgcn_mfma_f32_16x16x32_bf16(aF[2*ks],   bl, a0, 0, 0, 0);
            a0 = __builtin_amdgcn_mfma_f32_16x16x32_bf16(aF[2*ks],   bh, a0, 0, 0, 0);
            a1 = __builtin_amdgcn_mfma_f32_16x16x32_bf16(aF[2*ks+1], bl, a1, 0, 0, 0);
            a1 = __builtin_amdgcn_mfma_f32_16x16x32_bf16(aF[2*ks+1], bh, a1, 0, 0, 0);
          }
          const float b2c = b2m_s[(ct << 4) + l15];
          float p = 0.f;
          #pragma unroll
          for (int q = 0; q < 4; q++)
            p += fast_tanh(a0[q] + b2c) + fast_tanh(a1[q] + b2c);
          p += __shfl_xor(p, 16);
          p += __shfl_xor(p, 32);
          if (lane < 16) {
            const int c     = (ct << 4) + l15;
            const int plane = ((c >> 5) << 1) + (i >> 4);
            const int slot  = (i & 15) + (((c >> 3) & 3) << 4);
            const int elem  = c & 7;
            const unsigned short hb = f2bf(p);
            agfH[plane][slot][elem] = hb;
            agfL[plane][slot][elem] = f2bf(p - bf2f(hb));
          }
        }
      }
    }
    __syncthreads();   // (3) agf complete; u_s free

    // ---- Phase E1: hid = tanh([h|aggr] @ uw1^T + ub1) -> u_s.
    //      wave w: col-tile ct = w&7, row-half jt = w>>3 ----
    {
      const int ct = w & 7, jt = w >> 3;
      const int col = (ct << 4) + l15;
      const float bo = ub1[col];
      floatx4 acc = {0.f,0.f,0.f,0.f};
      #pragma unroll
      for (int ks = 0; ks < 8; ks++) {
        const int idx = (((l * 8 + ct) * 8 + ks) * 64 + lane) * 8;
        const short8 bh = *(const short8*)(g_wE1_h + idx);
        const short8 bl = *(const short8*)(g_wE1_l + idx);
        short8 ah, al;
        if (ks < 4) {
          ah = *(const short8*)&hfH[ks*2+jt][lane][0];
          al = *(const short8*)&hfL[ks*2+jt][lane][0];
        } else {
          ah = *(const short8*)&agfH[(ks-4)*2+jt][lane][0];
          al = *(const short8*)&agfL[(ks-4)*2+jt][lane][0];
        }
        acc = mfma3(ah, al, bh, bl, acc);
      }
      #pragma unroll
      for (int q = 0; q < 4; q++) {
        const int r = (jt << 4) + (l4 << 2) + q;
        u_s[r][col] = fast_tanh(acc[q] + bo);    // u_s reused as hid32
      }
    }
    __syncthreads();   // (4) hid32 ready AND all agf/hf reads done

    if (w < 8) cvt_plane(u_s, agfH, agfL, w, lane);   // hid frags into agf
    __syncthreads();   // (5)

    // ---- Phase E2: h += tanh(hid @ uw2^T + ub2); same (ct, jt) split ----
    {
      const int ct = w & 7, jt = w >> 3;
      const int col = (ct << 4) + l15;
      const float bo = ub2[col];
      floatx4 acc = {0.f,0.f,0.f,0.f};
      #pragma unroll
      for (int ks = 0; ks < 4; ks++) {
        const int idx = (((l * 8 + ct) * 4 + ks) * 64 + lane) * 8;
        const short8 bh = *(const short8*)(g_wE2_h + idx);
        const short8 bl = *(const short8*)(g_wE2_l + idx);
        const short8 ah = *(const short8*)&agfH[ks*2+jt][lane][0];
        const short8 al = *(const short8*)&agfL[ks*2+jt][lane][0];
        acc = mfma3(ah, al, bh, bl, acc);
      }
      #pragma unroll
      for (int q = 0; q < 4; q++) {
        const int r = (jt << 4) + (l4 << 2) + q;
        h32[r][col] += fast_tanh(acc[q] + bo);
      }
    }
    __syncthreads();   // (6) h updated

    if (l + 1 < NLAY) {
      if (w < 8) cvt_plane(h32, hfH, hfL, w, lane);
      __syncthreads();
    }
  }

  // ---------------- write out ----------------
  for (int idx = tid; idx < NN * EMB; idx += 1024)
    out[b * NN * EMB + idx] = h32[idx >> 7][idx & 127];
}

extern "C" void kernel_launch(void* const* d_in, const int* in_sizes, int n_in,
                              void* d_out, int out_size, void* d_ws, size_t ws_size,
                              hipStream_t stream) {
  const float* pos     = (const float*)d_in[0];
  const float* enc     = (const float*)d_in[1];
  const float* pos_emb = (const float*)d_in[2];
  const float* na_emb  = (const float*)d_in[3];
  const int*   T       = (const int*)d_in[4];
  // d_in[5] = num_agents (compile-time 32)
  const float* fc1_w = (const float*)d_in[6];
  const float* fc1_b = (const float*)d_in[7];
  const float* fc2_w = (const float*)d_in[8];
  const float* fc2_b = (const float*)d_in[9];
  const float* lin_w = (const float*)d_in[10];
  const float* lin_b = (const float*)d_in[11];
  const float* msg_w1 = (const float*)d_in[12];
  const float* msg_b1 = (const float*)d_in[13];
  const float* msg_w2 = (const float*)d_in[14];
  const float* msg_b2 = (const float*)d_in[15];
  const float* upd_w1 = (const float*)d_in[16];
  const float* upd_b1 = (const float*)d_in[17];
  const float* upd_w2 = (const float*)d_in[18];
  const float* upd_b2 = (const float*)d_in[19];

  wconv<<<192, 256, 0, stream>>>(msg_w1, msg_w2, upd_w1, upd_w2);
  fsd_fused<<<256, 1024, 0, stream>>>(pos, enc, pos_emb, na_emb, T,
      fc1_w, fc1_b, fc2_w, fc2_b, lin_w, lin_b,
      msg_w1, msg_b1, msg_b2, upd_b1, upd_b2,
      (float*)d_out);
}

// Round 9
// 207.743 us; speedup vs baseline: 1.3170x; 1.2118x over previous
//
#include <hip/hip_runtime.h>

#define NN   32
#define EMB  128
#define PEMB 64
#define ENCD 256
#define NLAY 4
#define W1C  261   // 2*EMB + 2*NCLS + 1
#define IND  193   // PEMB + 1 + EMB
#define UPAD 132   // padded row (floats): +16B breaks bank patterns
#define TSCALE 2.885390081777927f   // 2*log2(e): tanh(x) = 1 - 2/(exp2(TSCALE*x)+1)

typedef __attribute__((ext_vector_type(8))) short short8;
typedef __attribute__((ext_vector_type(4))) float floatx4;

// ---- pre-converted weight fragments (bf16 hi/lo, PRE-SCALED by TSCALE), filled by wconv ----
__device__ unsigned short g_wC_h[16384 * 8], g_wC_l[16384 * 8];   // W1 frags
__device__ unsigned short g_wD_h[8192 * 8],  g_wD_l[8192 * 8];    // W2 frags
__device__ unsigned short g_wE1_h[16384 * 8], g_wE1_l[16384 * 8]; // UW1 frags
__device__ unsigned short g_wE2_h[8192 * 8],  g_wE2_l[8192 * 8];  // UW2 frags

// tanh(x) = 1 - 2/(exp(2x)+1)   (Phase A only; unscaled weights there)
__device__ __forceinline__ float fast_tanh(float x) {
  float e = __expf(2.0f * x);
  return 1.0f - __fdividef(2.0f, e + 1.0f);
}
// tanh from PRE-SCALED input s = 2*log2(e)*x : exp2 + add + rcp + fma
__device__ __forceinline__ float tanh2(float s) {
  float e;
  asm("v_exp_f32 %0, %1" : "=v"(e) : "v"(s));
  const float ep1 = e + 1.0f;
  float r;
  asm("v_rcp_f32 %0, %1" : "=v"(r) : "v"(ep1));
  return __builtin_fmaf(-2.0f, r, 1.0f);
}
// fp32 -> bf16 RNE
__device__ __forceinline__ unsigned short f2bf(float x) {
  unsigned u = __float_as_uint(x);
  return (unsigned short)((u + 0x7fffu + ((u >> 16) & 1u)) >> 16);
}
__device__ __forceinline__ float bf2f(unsigned short h) {
  return __uint_as_float(((unsigned)h) << 16);
}
// hw packed convert: dst.lo16 = bf16(a), dst.hi16 = bf16(b)
__device__ __forceinline__ unsigned cvtpk(float a, float b) {
  unsigned r;
  asm("v_cvt_pk_bf16_f32 %0, %1, %2" : "=v"(r) : "v"(a), "v"(b));
  return r;
}

// A*B with A,B split hi/lo bf16 (drop lo*lo): 3 MFMAs
__device__ __forceinline__ floatx4 mfma3(short8 ah, short8 al, short8 bh, short8 bl, floatx4 acc) {
  acc = __builtin_amdgcn_mfma_f32_16x16x32_bf16(ah, bh, acc, 0, 0, 0);
  acc = __builtin_amdgcn_mfma_f32_16x16x32_bf16(al, bh, acc, 0, 0, 0);
  acc = __builtin_amdgcn_mfma_f32_16x16x32_bf16(ah, bl, acc, 0, 0, 0);
  return acc;
}

// one fragment plane p (jt=p&1, kstep=p>>1) from fp32 [NN][UPAD] -> hi/lo frag LDS
__device__ __forceinline__ void cvt_plane(const float (*src)[UPAD],
                                          unsigned short (*dH)[64][8],
                                          unsigned short (*dL)[64][8],
                                          int p, int lane) {
  const int row  = (lane & 15) + ((p & 1) << 4);
  const int koff = ((p >> 1) << 5) + ((lane >> 4) << 3);
  float x[8];
  *(float4*)&x[0] = *(const float4*)&src[row][koff];
  *(float4*)&x[4] = *(const float4*)&src[row][koff + 4];
  unsigned h[4], lo[4];
  #pragma unroll
  for (int q = 0; q < 4; q++) {
    h[q] = cvtpk(x[2*q], x[2*q+1]);
    const float r0 = x[2*q]   - __uint_as_float(h[q] << 16);
    const float r1 = x[2*q+1] - __uint_as_float(h[q] & 0xffff0000u);
    lo[q] = cvtpk(r0, r1);
  }
  *(uint4*)&dH[p][lane][0] = make_uint4(h[0], h[1], h[2], h[3]);
  *(uint4*)&dL[p][lane][0] = make_uint4(lo[0], lo[1], lo[2], lo[3]);
}

// t-fragment build from PRE-SCALED u,v,c5: tanh2 packed to bf16
__device__ __forceinline__ short8 build_t(const float* uv, const float* vv,
                                          float d, const float* c5q) {
  float t[8];
  #pragma unroll
  for (int m = 0; m < 8; m++) t[m] = tanh2(uv[m] + vv[m] + d * c5q[m]);
  uint4 p = make_uint4(cvtpk(t[0], t[1]), cvtpk(t[2], t[3]),
                       cvtpk(t[4], t[5]), cvtpk(t[6], t[7]));
  return *(short8*)&p;
}

__device__ __forceinline__ float dot16_lds(const float* base, const float* wreg) {
  const float4 a = *(const float4*)(base);
  const float4 b = *(const float4*)(base + 4);
  const float4 c = *(const float4*)(base + 8);
  const float4 d = *(const float4*)(base + 12);
  return a.x*wreg[0] + a.y*wreg[1] + a.z*wreg[2]  + a.w*wreg[3]
       + b.x*wreg[4] + b.y*wreg[5] + b.z*wreg[6]  + b.w*wreg[7]
       + c.x*wreg[8] + c.y*wreg[9] + c.z*wreg[10] + c.w*wreg[11]
       + d.x*wreg[12]+ d.y*wreg[13]+ d.z*wreg[14] + d.w*wreg[15];
}

// ---------------- weight pre-conversion: fp32 -> frag-ordered bf16 hi/lo, x TSCALE ----------------
__global__ __launch_bounds__(256) void wconv(
    const float* __restrict__ msg_w1, const float* __restrict__ msg_w2,
    const float* __restrict__ upd_w1, const float* __restrict__ upd_w2) {
  const int t = blockIdx.x * 256 + threadIdx.x;
  const float* src;
  unsigned short *dh, *dl;
  if (t < 16384) {                               // W1 (Phase C): [l][tile][ks][lane][8]
    const int lane = t & 63, ks = (t >> 6) & 3, tile = (t >> 8) & 15, l = t >> 12;
    src = msg_w1 + l * EMB * W1C + (((tile & 7) << 4) + (lane & 15)) * W1C
        + (tile >> 3) * EMB + ks * 32 + ((lane >> 4) << 3);
    dh = g_wC_h + t * 8; dl = g_wC_l + t * 8;
  } else if (t < 24576) {                        // W2 (Phase D): [l][ct][ks][lane][8]
    const int r = t - 16384;
    const int lane = r & 63, ks = (r >> 6) & 3, ct = (r >> 8) & 7, l = r >> 11;
    src = msg_w2 + l * EMB * EMB + ((ct << 4) + (lane & 15)) * EMB + ks * 32 + ((lane >> 4) << 3);
    dh = g_wD_h + r * 8; dl = g_wD_l + r * 8;
  } else if (t < 40960) {                        // UW1 (E1): [l][ct][ks(8)][lane][8]
    const int r = t - 24576;
    const int lane = r & 63, ks = (r >> 6) & 7, ct = (r >> 9) & 7, l = r >> 12;
    src = upd_w1 + l * EMB * 2 * EMB + ((ct << 4) + (lane & 15)) * 2 * EMB + ks * 32 + ((lane >> 4) << 3);
    dh = g_wE1_h + r * 8; dl = g_wE1_l + r * 8;
  } else if (t < 49152) {                        // UW2 (E2): [l][ct][ks(4)][lane][8]
    const int r = t - 40960;
    const int lane = r & 63, ks = (r >> 6) & 3, ct = (r >> 8) & 7, l = r >> 11;
    src = upd_w2 + l * EMB * EMB + ((ct << 4) + (lane & 15)) * EMB + ks * 32 + ((lane >> 4) << 3);
    dh = g_wE2_h + r * 8; dl = g_wE2_l + r * 8;
  } else return;
  unsigned short hh[8], ll[8];
  #pragma unroll
  for (int m = 0; m < 8; m++) {
    const float x = src[m] * TSCALE;             // fold tanh 2*log2e pre-scale into weights
    const unsigned short hb = f2bf(x);
    hh[m] = hb;
    ll[m] = f2bf(x - bf2f(hb));
  }
  *(short8*)dh = *(const short8*)hh;
  *(short8*)dl = *(const short8*)ll;
}

__global__ __launch_bounds__(1024)
__attribute__((amdgpu_waves_per_eu(4, 4)))     // 4 waves/EU: 128 total regs/wave (64 arch + 64 AGPR)
void fsd_fused(
    const float* __restrict__ pos, const float* __restrict__ enc,
    const float* __restrict__ pos_emb, const float* __restrict__ na_emb,
    const int* __restrict__ T,
    const float* __restrict__ fc1_w, const float* __restrict__ fc1_b,
    const float* __restrict__ fc2_w, const float* __restrict__ fc2_b,
    const float* __restrict__ lin_w, const float* __restrict__ lin_b,
    const float* __restrict__ msg_w1, const float* __restrict__ msg_b1,
    const float* __restrict__ msg_b2,
    const float* __restrict__ upd_b1, const float* __restrict__ upd_b2,
    float* __restrict__ out)
{
  __shared__ __align__(16) float h32[NN][UPAD];
  __shared__ __align__(16) float u_s[NN][UPAD];     // pos_emb staging; hid32 in E1
  __shared__ __align__(16) float v_s[NN][UPAD];
  __shared__ __align__(16) unsigned short hfH[8][64][8],  hfL[8][64][8];   // h A-frags
  __shared__ __align__(16) unsigned short agfH[8][64][8], agfL[8][64][8];  // aggr A-frags; hid frags in E2
  __shared__ __align__(16) unsigned short w2fH[8][4][64][8], w2fL[8][4][64][8]; // W2 B-frags (64 KB)
  __shared__ float e_s[EMB];
  __shared__ float c5_s[EMB];
  __shared__ float b2m_s[EMB];
  __shared__ float clsU[2][EMB], clsV[2][EMB];
  __shared__ float enc_s[ENCD];
  __shared__ float hidA_s[64];
  __shared__ float posx_s[NN], posy_s[NN];
  __shared__ int   T_s[NN];

  const int b    = blockIdx.x;
  const int tid  = threadIdx.x;
  const int w    = tid >> 6, lane = tid & 63;   // 16 waves
  const int o    = tid & 127, g8 = tid >> 7;    // [0,8): node-group for VALU phases
  const int l15  = lane & 15, l4 = lane >> 4;

  // ---------------- Phase A: decoder_fc -> e_s ----------------
  if (tid < ENCD) enc_s[tid] = enc[b * ENCD + tid];
  if (tid < NN) {
    posx_s[tid] = pos[(b * NN + tid) * 2 + 0];
    posy_s[tid] = pos[(b * NN + tid) * 2 + 1];
    T_s[tid]    = T[b * NN + tid];
  }
  __syncthreads();
  if (tid < 64) {
    float a = fc1_b[tid];
    const float* wr = fc1_w + tid * ENCD;
    #pragma unroll 8
    for (int k = 0; k < ENCD; k++) a += enc_s[k] * wr[k];
    hidA_s[tid] = fast_tanh(a);
  }
  __syncthreads();
  if (tid < EMB) {
    float a = fc2_b[tid];
    const float* wr = fc2_w + tid * 64;
    #pragma unroll 8
    for (int k = 0; k < 64; k++) a += hidA_s[k] * wr[k];
    e_s[tid] = a;
  }
  float* pe_s = &u_s[0][0];
  for (int idx = tid; idx < NN * PEMB; idx += 1024)
    pe_s[idx] = pos_emb[b * NN * PEMB + idx];
  __syncthreads();

  // ---------------- Phase B: h0 = x @ lin_w^T + lin_b (unscaled, no tanh) ----------------
  {
    const float nav = na_emb[b];
    const float* wr = lin_w + o * IND;
    float ebias = lin_b[o] + nav * wr[PEMB];
    #pragma unroll 8
    for (int k = 0; k < EMB; k++) ebias += e_s[k] * wr[65 + k];
    float acc[4];
    #pragma unroll
    for (int n = 0; n < 4; n++) acc[n] = ebias;
    for (int kc = 0; kc < PEMB; kc += 16) {
      float wreg[16];
      #pragma unroll
      for (int q = 0; q < 16; q++) wreg[q] = wr[kc + q];
      #pragma unroll
      for (int n = 0; n < 4; n++)
        acc[n] += dot16_lds(&pe_s[(g8 + 8 * n) * PEMB + kc], wreg);
    }
    __syncthreads();   // pe reads done before u_s reuse
    #pragma unroll
    for (int n = 0; n < 4; n++) h32[g8 + 8 * n][o] = acc[n];
  }
  __syncthreads();
  if (w < 8) cvt_plane(h32, hfH, hfL, w, lane);
  __syncthreads();

  // ---------------- Layer loop ----------------
  for (int l = 0; l < NLAY; l++) {
    const float* b1  = msg_b1 + l * EMB;
    const float* b2  = msg_b2 + l * EMB;
    const float* ub1 = upd_b1 + l * EMB;
    const float* ub2 = upd_b2 + l * EMB;
    const float* w1  = msg_w1 + l * EMB * W1C;   // c5/cls columns only

    // ---- stage (all tanh-input tables PRE-SCALED by TSCALE) ----
    if (tid < EMB) { c5_s[tid] = w1[tid * W1C + 260] * TSCALE; b2m_s[tid] = b2[tid] * TSCALE; }
    {
      const int c = (tid >> 7) & 1, oo = tid & 127;
      if (tid < 256)      clsU[c][oo] = (b1[oo] + w1[oo * W1C + 258 + c]) * TSCALE;
      else if (tid < 512) clsV[c][oo] = w1[oo * W1C + 256 + c] * TSCALE;
    }
    {
      const unsigned short* sH = g_wD_h + l * 16384;
      const unsigned short* sL = g_wD_l + l * 16384;
      unsigned short* dH = &w2fH[0][0][0][0];
      unsigned short* dL = &w2fL[0][0][0][0];
      for (int idx = tid; idx < 2048; idx += 1024) {
        *(short8*)(dH + idx * 8) = *(const short8*)(sH + idx * 8);
        *(short8*)(dL + idx * 8) = *(const short8*)(sL + idx * 8);
      }
    }
    __syncthreads();   // (1) tables + w2f ready, h-frags ready

    // ---- Phase C: u,v = h @ W1parts^T via MFMA (outputs scaled); wave w owns col-tile w ----
    {
      const int part = w >> 3;                   // 0 -> u, 1 -> v
      const int col  = ((w & 7) << 4) + l15;
      floatx4 acc0 = {0.f,0.f,0.f,0.f}, acc1 = {0.f,0.f,0.f,0.f};
      #pragma unroll
      for (int ks = 0; ks < 4; ks++) {
        const int idx = (((l * 16 + w) * 4 + ks) * 64 + lane) * 8;
        const short8 bh = *(const short8*)(g_wC_h + idx);
        const short8 bl = *(const short8*)(g_wC_l + idx);
        const short8 ah0 = *(const short8*)&hfH[ks*2+0][lane][0];
        const short8 al0 = *(const short8*)&hfL[ks*2+0][lane][0];
        const short8 ah1 = *(const short8*)&hfH[ks*2+1][lane][0];
        const short8 al1 = *(const short8*)&hfL[ks*2+1][lane][0];
        acc0 = mfma3(ah0, al0, bh, bl, acc0);
        acc1 = mfma3(ah1, al1, bh, bl, acc1);
      }
      float (*dst)[UPAD] = part ? v_s : u_s;
      const float (*tab)[EMB] = part ? clsV : clsU;
      #pragma unroll
      for (int q = 0; q < 4; q++) {
        const int r0 = (l4 << 2) + q;
        const int r1 = r0 + 16;
        dst[r0][col] = acc0[q] + tab[T_s[r0]][col];
        dst[r1][col] = acc1[q] + tab[T_s[r1]][col];
      }
    }
    __syncthreads();   // (2) u,v ready

    // ---- Phase D: wave w owns dst nodes 2w, 2w+1 sequentially.
    //      Persistent state = acc[8][2] (64 AGPRs); t-planes transient (8 arch regs). ----
    {
      const int j0 = l15, j1 = l15 + 16;
      const float pj0x = posx_s[j0], pj0y = posy_s[j0];
      const float pj1x = posx_s[j1], pj1y = posy_s[j1];
      for (int ii = 0; ii < 2; ii++) {
        const int i = (w << 1) + ii;
        const float pix = posx_s[i], piy = posy_s[i];
        float dx0 = pj0x - pix, dy0 = pj0y - piy;
        float dx1 = pj1x - pix, dy1 = pj1y - piy;
        const float d0 = sqrtf(dx0 * dx0 + dy0 * dy0);
        const float d1 = sqrtf(dx1 * dx1 + dy1 * dy1);

        floatx4 acc[8][2];
        #pragma unroll
        for (int ct = 0; ct < 8; ct++) {
          acc[ct][0] = (floatx4){0.f,0.f,0.f,0.f};
          acc[ct][1] = (floatx4){0.f,0.f,0.f,0.f};
        }
        #pragma unroll
        for (int q = 0; q < 4; q++) {            // k-range q*32 + l4*8
          const int k8 = (q << 5) + (l4 << 3);
          float v0[8], v1[8], c5q[8], uv[8];
          *(float4*)&v0[0]  = *(const float4*)&v_s[j0][k8];
          *(float4*)&v0[4]  = *(const float4*)&v_s[j0][k8 + 4];
          *(float4*)&v1[0]  = *(const float4*)&v_s[j1][k8];
          *(float4*)&v1[4]  = *(const float4*)&v_s[j1][k8 + 4];
          *(float4*)&c5q[0] = *(const float4*)&c5_s[k8];
          *(float4*)&c5q[4] = *(const float4*)&c5_s[k8 + 4];
          *(float4*)&uv[0]  = *(const float4*)&u_s[i][k8];
          *(float4*)&uv[4]  = *(const float4*)&u_s[i][k8 + 4];
          const short8 aF0 = build_t(uv, v0, d0, c5q);
          const short8 aF1 = build_t(uv, v1, d1, c5q);
          #pragma unroll
          for (int ct = 0; ct < 8; ct++) {
            const short8 bh = *(const short8*)&w2fH[ct][q][lane][0];
            const short8 bl = *(const short8*)&w2fL[ct][q][lane][0];
            acc[ct][0] = __builtin_amdgcn_mfma_f32_16x16x32_bf16(aF0, bl, acc[ct][0], 0, 0, 0);
            acc[ct][0] = __builtin_amdgcn_mfma_f32_16x16x32_bf16(aF0, bh, acc[ct][0], 0, 0, 0);
            acc[ct][1] = __builtin_amdgcn_mfma_f32_16x16x32_bf16(aF1, bl, acc[ct][1], 0, 0, 0);
            acc[ct][1] = __builtin_amdgcn_mfma_f32_16x16x32_bf16(aF1, bh, acc[ct][1], 0, 0, 0);
          }
        }
        // epilogue: m = tanh2(C + b2scaled), aggregate over j rows, scatter to agf
        #pragma unroll
        for (int ct = 0; ct < 8; ct++) {
          const float b2c = b2m_s[(ct << 4) + l15];
          float p = 0.f;
          #pragma unroll
          for (int q = 0; q < 4; q++)
            p += tanh2(acc[ct][0][q] + b2c) + tanh2(acc[ct][1][q] + b2c);
          p += __shfl_xor(p, 16);
          p += __shfl_xor(p, 32);
          if (lane < 16) {
            const int c     = (ct << 4) + l15;
            const int plane = ((c >> 5) << 1) + (i >> 4);
            const int slot  = (i & 15) + (((c >> 3) & 3) << 4);
            const int elem  = c & 7;
            const unsigned short hb = f2bf(p);
            agfH[plane][slot][elem] = hb;
            agfL[plane][slot][elem] = f2bf(p - bf2f(hb));
          }
        }
      }
    }
    __syncthreads();   // (3) agf complete; u_s free

    // ---- Phase E1: hid = tanh2([h|aggr] @ uw1s^T + ub1*S) -> u_s.
    //      wave w: col-tile ct = w&7, row-half jt = w>>3 ----
    {
      const int ct = w & 7, jt = w >> 3;
      const int col = (ct << 4) + l15;
      const float bo = ub1[col] * TSCALE;
      floatx4 acc = {0.f,0.f,0.f,0.f};
      #pragma unroll
      for (int ks = 0; ks < 8; ks++) {
        const int idx = (((l * 8 + ct) * 8 + ks) * 64 + lane) * 8;
        const short8 bh = *(const short8*)(g_wE1_h + idx);
        const short8 bl = *(const short8*)(g_wE1_l + idx);
        short8 ah, al;
        if (ks < 4) {
          ah = *(const short8*)&hfH[ks*2+jt][lane][0];
          al = *(const short8*)&hfL[ks*2+jt][lane][0];
        } else {
          ah = *(const short8*)&agfH[(ks-4)*2+jt][lane][0];
          al = *(const short8*)&agfL[(ks-4)*2+jt][lane][0];
        }
        acc = mfma3(ah, al, bh, bl, acc);
      }
      #pragma unroll
      for (int q = 0; q < 4; q++) {
        const int r = (jt << 4) + (l4 << 2) + q;
        u_s[r][col] = tanh2(acc[q] + bo);        // u_s reused as hid32 (unscaled output)
      }
    }
    __syncthreads();   // (4) hid32 ready AND all agf/hf reads done

    if (w < 8) cvt_plane(u_s, agfH, agfL, w, lane);   // hid frags into agf
    __syncthreads();   // (5)

    // ---- Phase E2: h += tanh2(hid @ uw2s^T + ub2*S); same (ct, jt) split ----
    {
      const int ct = w & 7, jt = w >> 3;
      const int col = (ct << 4) + l15;
      const float bo = ub2[col] * TSCALE;
      floatx4 acc = {0.f,0.f,0.f,0.f};
      #pragma unroll
      for (int ks = 0; ks < 4; ks++) {
        const int idx = (((l * 8 + ct) * 4 + ks) * 64 + lane) * 8;
        const short8 bh = *(const short8*)(g_wE2_h + idx);
        const short8 bl = *(const short8*)(g_wE2_l + idx);
        const short8 ah = *(const short8*)&agfH[ks*2+jt][lane][0];
        const short8 al = *(const short8*)&agfL[ks*2+jt][lane][0];
        acc = mfma3(ah, al, bh, bl, acc);
      }
      #pragma unroll
      for (int q = 0; q < 4; q++) {
        const int r = (jt << 4) + (l4 << 2) + q;
        h32[r][col] += tanh2(acc[q] + bo);
      }
    }
    __syncthreads();   // (6) h updated

    if (l + 1 < NLAY) {
      if (w < 8) cvt_plane(h32, hfH, hfL, w, lane);
      __syncthreads();
    }
  }

  // ---------------- write out ----------------
  for (int idx = tid; idx < NN * EMB; idx += 1024)
    out[b * NN * EMB + idx] = h32[idx >> 7][idx & 127];
}

extern "C" void kernel_launch(void* const* d_in, const int* in_sizes, int n_in,
                              void* d_out, int out_size, void* d_ws, size_t ws_size,
                              hipStream_t stream) {
  const float* pos     = (const float*)d_in[0];
  const float* enc     = (const float*)d_in[1];
  const float* pos_emb = (const float*)d_in[2];
  const float* na_emb  = (const float*)d_in[3];
  const int*   T       = (const int*)d_in[4];
  // d_in[5] = num_agents (compile-time 32)
  const float* fc1_w = (const float*)d_in[6];
  const float* fc1_b = (const float*)d_in[7];
  const float* fc2_w = (const float*)d_in[8];
  const float* fc2_b = (const float*)d_in[9];
  const float* lin_w = (const float*)d_in[10];
  const float* lin_b = (const float*)d_in[11];
  const float* msg_w1 = (const float*)d_in[12];
  const float* msg_b1 = (const float*)d_in[13];
  const float* msg_w2 = (const float*)d_in[14];
  const float* msg_b2 = (const float*)d_in[15];
  const float* upd_w1 = (const float*)d_in[16];
  const float* upd_b1 = (const float*)d_in[17];
  const float* upd_w2 = (const float*)d_in[18];
  const float* upd_b2 = (const float*)d_in[19];

  wconv<<<192, 256, 0, stream>>>(msg_w1, msg_w2, upd_w1, upd_w2);
  fsd_fused<<<256, 1024, 0, stream>>>(pos, enc, pos_emb, na_emb, T,
      fc1_w, fc1_b, fc2_w, fc2_b, lin_w, lin_b,
      msg_w1, msg_b1, msg_b2, upd_b1, upd_b2,
      (float*)d_out);
}

// Round 10
// 171.047 us; speedup vs baseline: 1.5996x; 1.2145x over previous
//
#include <hip/hip_runtime.h>

#define NN   32
#define EMB  128
#define PEMB 64
#define ENCD 256
#define NLAY 4
#define W1C  261   // 2*EMB + 2*NCLS + 1
#define IND  193   // PEMB + 1 + EMB
#define UPAD 132   // padded row (floats): +16B breaks bank patterns
#define TSCALE 2.885390081777927f   // 2*log2(e): tanh(x) = 1 - 2/(exp2(TSCALE*x)+1)

typedef __attribute__((ext_vector_type(8))) short short8;
typedef __attribute__((ext_vector_type(4))) float floatx4;

// ---- pre-converted weight fragments (bf16 hi/lo, PRE-SCALED by TSCALE), filled by wconv ----
__device__ unsigned short g_wC_h[16384 * 8], g_wC_l[16384 * 8];   // W1 frags
__device__ unsigned short g_wD_h[8192 * 8],  g_wD_l[8192 * 8];    // W2 frags
__device__ unsigned short g_wE1_h[16384 * 8], g_wE1_l[16384 * 8]; // UW1 frags
__device__ unsigned short g_wE2_h[8192 * 8],  g_wE2_l[8192 * 8];  // UW2 frags

// tanh(x) = 1 - 2/(exp(2x)+1)   (Phase A only; unscaled weights there)
__device__ __forceinline__ float fast_tanh(float x) {
  float e = __expf(2.0f * x);
  return 1.0f - __fdividef(2.0f, e + 1.0f);
}
// tanh from PRE-SCALED input s = 2*log2(e)*x : exp2 + add + rcp + fma
__device__ __forceinline__ float tanh2(float s) {
  float e;
  asm("v_exp_f32 %0, %1" : "=v"(e) : "v"(s));
  const float ep1 = e + 1.0f;
  float r;
  asm("v_rcp_f32 %0, %1" : "=v"(r) : "v"(ep1));
  return __builtin_fmaf(-2.0f, r, 1.0f);
}
// fp32 -> bf16 RNE
__device__ __forceinline__ unsigned short f2bf(float x) {
  unsigned u = __float_as_uint(x);
  return (unsigned short)((u + 0x7fffu + ((u >> 16) & 1u)) >> 16);
}
__device__ __forceinline__ float bf2f(unsigned short h) {
  return __uint_as_float(((unsigned)h) << 16);
}
// hw packed convert: dst.lo16 = bf16(a), dst.hi16 = bf16(b)
__device__ __forceinline__ unsigned cvtpk(float a, float b) {
  unsigned r;
  asm("v_cvt_pk_bf16_f32 %0, %1, %2" : "=v"(r) : "v"(a), "v"(b));
  return r;
}

// A*B with A,B split hi/lo bf16 (drop lo*lo): 3 MFMAs
__device__ __forceinline__ floatx4 mfma3(short8 ah, short8 al, short8 bh, short8 bl, floatx4 acc) {
  acc = __builtin_amdgcn_mfma_f32_16x16x32_bf16(ah, bh, acc, 0, 0, 0);
  acc = __builtin_amdgcn_mfma_f32_16x16x32_bf16(al, bh, acc, 0, 0, 0);
  acc = __builtin_amdgcn_mfma_f32_16x16x32_bf16(ah, bl, acc, 0, 0, 0);
  return acc;
}

// one fragment plane p (jt=p&1, kstep=p>>1) from fp32 [NN][UPAD] -> hi/lo frag LDS
__device__ __forceinline__ void cvt_plane(const float (*src)[UPAD],
                                          unsigned short (*dH)[64][8],
                                          unsigned short (*dL)[64][8],
                                          int p, int lane) {
  const int row  = (lane & 15) + ((p & 1) << 4);
  const int koff = ((p >> 1) << 5) + ((lane >> 4) << 3);
  float x[8];
  *(float4*)&x[0] = *(const float4*)&src[row][koff];
  *(float4*)&x[4] = *(const float4*)&src[row][koff + 4];
  unsigned h[4], lo[4];
  #pragma unroll
  for (int q = 0; q < 4; q++) {
    h[q] = cvtpk(x[2*q], x[2*q+1]);
    const float r0 = x[2*q]   - __uint_as_float(h[q] << 16);
    const float r1 = x[2*q+1] - __uint_as_float(h[q] & 0xffff0000u);
    lo[q] = cvtpk(r0, r1);
  }
  *(uint4*)&dH[p][lane][0] = make_uint4(h[0], h[1], h[2], h[3]);
  *(uint4*)&dL[p][lane][0] = make_uint4(lo[0], lo[1], lo[2], lo[3]);
}

// t-fragment build from PRE-SCALED u,v,c5: tanh2 packed to bf16
__device__ __forceinline__ short8 build_t(const float* uv, const float* vv,
                                          float d, const float* c5q) {
  float t[8];
  #pragma unroll
  for (int m = 0; m < 8; m++) t[m] = tanh2(uv[m] + vv[m] + d * c5q[m]);
  uint4 p = make_uint4(cvtpk(t[0], t[1]), cvtpk(t[2], t[3]),
                       cvtpk(t[4], t[5]), cvtpk(t[6], t[7]));
  return *(short8*)&p;
}

__device__ __forceinline__ float dot16_lds(const float* base, const float* wreg) {
  const float4 a = *(const float4*)(base);
  const float4 b = *(const float4*)(base + 4);
  const float4 c = *(const float4*)(base + 8);
  const float4 d = *(const float4*)(base + 12);
  return a.x*wreg[0] + a.y*wreg[1] + a.z*wreg[2]  + a.w*wreg[3]
       + b.x*wreg[4] + b.y*wreg[5] + b.z*wreg[6]  + b.w*wreg[7]
       + c.x*wreg[8] + c.y*wreg[9] + c.z*wreg[10] + c.w*wreg[11]
       + d.x*wreg[12]+ d.y*wreg[13]+ d.z*wreg[14] + d.w*wreg[15];
}

// ---------------- weight pre-conversion: fp32 -> frag-ordered bf16 hi/lo, x TSCALE ----------------
__global__ __launch_bounds__(256) void wconv(
    const float* __restrict__ msg_w1, const float* __restrict__ msg_w2,
    const float* __restrict__ upd_w1, const float* __restrict__ upd_w2) {
  const int t = blockIdx.x * 256 + threadIdx.x;
  const float* src;
  unsigned short *dh, *dl;
  if (t < 16384) {                               // W1 (Phase C): [l][tile][ks][lane][8]
    const int lane = t & 63, ks = (t >> 6) & 3, tile = (t >> 8) & 15, l = t >> 12;
    src = msg_w1 + l * EMB * W1C + (((tile & 7) << 4) + (lane & 15)) * W1C
        + (tile >> 3) * EMB + ks * 32 + ((lane >> 4) << 3);
    dh = g_wC_h + t * 8; dl = g_wC_l + t * 8;
  } else if (t < 24576) {                        // W2 (Phase D): [l][ct][ks][lane][8]
    const int r = t - 16384;
    const int lane = r & 63, ks = (r >> 6) & 3, ct = (r >> 8) & 7, l = r >> 11;
    src = msg_w2 + l * EMB * EMB + ((ct << 4) + (lane & 15)) * EMB + ks * 32 + ((lane >> 4) << 3);
    dh = g_wD_h + r * 8; dl = g_wD_l + r * 8;
  } else if (t < 40960) {                        // UW1 (E1): [l][ct][ks(8)][lane][8]
    const int r = t - 24576;
    const int lane = r & 63, ks = (r >> 6) & 7, ct = (r >> 9) & 7, l = r >> 12;
    src = upd_w1 + l * EMB * 2 * EMB + ((ct << 4) + (lane & 15)) * 2 * EMB + ks * 32 + ((lane >> 4) << 3);
    dh = g_wE1_h + r * 8; dl = g_wE1_l + r * 8;
  } else if (t < 49152) {                        // UW2 (E2): [l][ct][ks(4)][lane][8]
    const int r = t - 40960;
    const int lane = r & 63, ks = (r >> 6) & 3, ct = (r >> 8) & 7, l = r >> 11;
    src = upd_w2 + l * EMB * EMB + ((ct << 4) + (lane & 15)) * EMB + ks * 32 + ((lane >> 4) << 3);
    dh = g_wE2_h + r * 8; dl = g_wE2_l + r * 8;
  } else return;
  unsigned short hh[8], ll[8];
  #pragma unroll
  for (int m = 0; m < 8; m++) {
    const float x = src[m] * TSCALE;             // fold tanh 2*log2e pre-scale into weights
    const unsigned short hb = f2bf(x);
    hh[m] = hb;
    ll[m] = f2bf(x - bf2f(hb));
  }
  *(short8*)dh = *(const short8*)hh;
  *(short8*)dl = *(const short8*)ll;
}

__global__ __launch_bounds__(1024)
__attribute__((amdgpu_waves_per_eu(4, 4)))     // 4 waves/EU: 128 total regs/wave (64 arch + 64 AGPR)
void fsd_fused(
    const float* __restrict__ pos, const float* __restrict__ enc,
    const float* __restrict__ pos_emb, const float* __restrict__ na_emb,
    const int* __restrict__ T,
    const float* __restrict__ fc1_w, const float* __restrict__ fc1_b,
    const float* __restrict__ fc2_w, const float* __restrict__ fc2_b,
    const float* __restrict__ lin_w, const float* __restrict__ lin_b,
    const float* __restrict__ msg_w1, const float* __restrict__ msg_b1,
    const float* __restrict__ msg_b2,
    const float* __restrict__ upd_b1, const float* __restrict__ upd_b2,
    float* __restrict__ out)
{
  __shared__ __align__(16) float h32[NN][UPAD];
  __shared__ __align__(16) float u_s[NN][UPAD];     // pos_emb staging; hid32 in E1
  __shared__ __align__(16) float v_s[NN][UPAD];
  __shared__ __align__(16) unsigned short hfH[8][64][8],  hfL[8][64][8];   // h A-frags
  __shared__ __align__(16) unsigned short agfH[8][64][8], agfL[8][64][8];  // aggr A-frags; hid frags in E2
  __shared__ __align__(16) unsigned short w2fH[8][4][64][8], w2fL[8][4][64][8]; // W2 B-frags (64 KB)
  __shared__ float e_s[EMB];
  __shared__ float c5_s[EMB];
  __shared__ float b2m_s[EMB];
  __shared__ float clsU[2][EMB], clsV[2][EMB];
  __shared__ float enc_s[ENCD];
  __shared__ float hidA_s[64];
  __shared__ float posx_s[NN], posy_s[NN];
  __shared__ int   T_s[NN];

  const int b    = blockIdx.x;
  const int tid  = threadIdx.x;
  const int w    = tid >> 6, lane = tid & 63;   // 16 waves
  const int o    = tid & 127, g8 = tid >> 7;    // [0,8): node-group for VALU phases
  const int l15  = lane & 15, l4 = lane >> 4;

  // ---------------- Phase A: decoder_fc -> e_s ----------------
  if (tid < ENCD) enc_s[tid] = enc[b * ENCD + tid];
  if (tid < NN) {
    posx_s[tid] = pos[(b * NN + tid) * 2 + 0];
    posy_s[tid] = pos[(b * NN + tid) * 2 + 1];
    T_s[tid]    = T[b * NN + tid];
  }
  __syncthreads();
  if (tid < 64) {
    float a = fc1_b[tid];
    const float* wr = fc1_w + tid * ENCD;
    #pragma unroll 8
    for (int k = 0; k < ENCD; k++) a += enc_s[k] * wr[k];
    hidA_s[tid] = fast_tanh(a);
  }
  __syncthreads();
  if (tid < EMB) {
    float a = fc2_b[tid];
    const float* wr = fc2_w + tid * 64;
    #pragma unroll 8
    for (int k = 0; k < 64; k++) a += hidA_s[k] * wr[k];
    e_s[tid] = a;
  }
  float* pe_s = &u_s[0][0];
  for (int idx = tid; idx < NN * PEMB; idx += 1024)
    pe_s[idx] = pos_emb[b * NN * PEMB + idx];
  __syncthreads();

  // ---------------- Phase B: h0 = x @ lin_w^T + lin_b (unscaled, no tanh) ----------------
  {
    const float nav = na_emb[b];
    const float* wr = lin_w + o * IND;
    float ebias = lin_b[o] + nav * wr[PEMB];
    #pragma unroll 8
    for (int k = 0; k < EMB; k++) ebias += e_s[k] * wr[65 + k];
    float acc[4];
    #pragma unroll
    for (int n = 0; n < 4; n++) acc[n] = ebias;
    for (int kc = 0; kc < PEMB; kc += 16) {
      float wreg[16];
      #pragma unroll
      for (int q = 0; q < 16; q++) wreg[q] = wr[kc + q];
      #pragma unroll
      for (int n = 0; n < 4; n++)
        acc[n] += dot16_lds(&pe_s[(g8 + 8 * n) * PEMB + kc], wreg);
    }
    __syncthreads();   // pe reads done before u_s reuse
    #pragma unroll
    for (int n = 0; n < 4; n++) h32[g8 + 8 * n][o] = acc[n];
  }
  __syncthreads();
  if (w < 8) cvt_plane(h32, hfH, hfL, w, lane);
  __syncthreads();

  // ---------------- Layer loop ----------------
  for (int l = 0; l < NLAY; l++) {
    const float* b1  = msg_b1 + l * EMB;
    const float* b2  = msg_b2 + l * EMB;
    const float* ub1 = upd_b1 + l * EMB;
    const float* ub2 = upd_b2 + l * EMB;
    const float* w1  = msg_w1 + l * EMB * W1C;   // c5/cls columns only

    // ---- stage (all tanh-input tables PRE-SCALED by TSCALE) ----
    if (tid < EMB) { c5_s[tid] = w1[tid * W1C + 260] * TSCALE; b2m_s[tid] = b2[tid] * TSCALE; }
    {
      const int c = (tid >> 7) & 1, oo = tid & 127;
      if (tid < 256)      clsU[c][oo] = (b1[oo] + w1[oo * W1C + 258 + c]) * TSCALE;
      else if (tid < 512) clsV[c][oo] = w1[oo * W1C + 256 + c] * TSCALE;
    }
    {
      const unsigned short* sH = g_wD_h + l * 16384;
      const unsigned short* sL = g_wD_l + l * 16384;
      unsigned short* dH = &w2fH[0][0][0][0];
      unsigned short* dL = &w2fL[0][0][0][0];
      for (int idx = tid; idx < 2048; idx += 1024) {
        *(short8*)(dH + idx * 8) = *(const short8*)(sH + idx * 8);
        *(short8*)(dL + idx * 8) = *(const short8*)(sL + idx * 8);
      }
    }
    __syncthreads();   // (1) tables + w2f ready, h-frags ready

    // ---- Phase C: u,v = h @ W1parts^T via MFMA (outputs scaled); wave w owns col-tile w ----
    {
      const int part = w >> 3;                   // 0 -> u, 1 -> v
      const int col  = ((w & 7) << 4) + l15;
      floatx4 acc0 = {0.f,0.f,0.f,0.f}, acc1 = {0.f,0.f,0.f,0.f};
      #pragma unroll
      for (int ks = 0; ks < 4; ks++) {
        const int idx = (((l * 16 + w) * 4 + ks) * 64 + lane) * 8;
        const short8 bh = *(const short8*)(g_wC_h + idx);
        const short8 bl = *(const short8*)(g_wC_l + idx);
        const short8 ah0 = *(const short8*)&hfH[ks*2+0][lane][0];
        const short8 al0 = *(const short8*)&hfL[ks*2+0][lane][0];
        const short8 ah1 = *(const short8*)&hfH[ks*2+1][lane][0];
        const short8 al1 = *(const short8*)&hfL[ks*2+1][lane][0];
        acc0 = mfma3(ah0, al0, bh, bl, acc0);
        acc1 = mfma3(ah1, al1, bh, bl, acc1);
      }
      float (*dst)[UPAD] = part ? v_s : u_s;
      const float (*tab)[EMB] = part ? clsV : clsU;
      #pragma unroll
      for (int q = 0; q < 4; q++) {
        const int r0 = (l4 << 2) + q;
        const int r1 = r0 + 16;
        dst[r0][col] = acc0[q] + tab[T_s[r0]][col];
        dst[r1][col] = acc1[q] + tab[T_s[r1]][col];
      }
    }
    __syncthreads();   // (2) u,v ready

    // ---- Phase D: wave w owns dst nodes 2w, 2w+1; jt-half-planes SEQUENTIAL.
    //      acc[8] = 32 AGPRs, one t-frag live, psum[8] carries cross-jt partials. ----
    {
      #pragma unroll 1
      for (int ii = 0; ii < 2; ii++) {
        const int i = (w << 1) + ii;
        const float pix = posx_s[i], piy = posy_s[i];
        float psum[8];
        #pragma unroll
        for (int ct = 0; ct < 8; ct++) psum[ct] = 0.f;

        #pragma unroll 1
        for (int jt = 0; jt < 2; jt++) {
          const int jr = l15 + (jt << 4);
          const float dxx = posx_s[jr] - pix, dyy = posy_s[jr] - piy;
          const float d = sqrtf(dxx * dxx + dyy * dyy);
          floatx4 acc[8];
          #pragma unroll
          for (int ct = 0; ct < 8; ct++) acc[ct] = (floatx4){0.f,0.f,0.f,0.f};

          #pragma unroll 1
          for (int q = 0; q < 4; q++) {          // k-range q*32 + l4*8
            const int k8 = (q << 5) + (l4 << 3);
            float uv[8], vv[8], c5q[8];
            *(float4*)&uv[0]  = *(const float4*)&u_s[i][k8];
            *(float4*)&uv[4]  = *(const float4*)&u_s[i][k8 + 4];
            *(float4*)&vv[0]  = *(const float4*)&v_s[jr][k8];
            *(float4*)&vv[4]  = *(const float4*)&v_s[jr][k8 + 4];
            *(float4*)&c5q[0] = *(const float4*)&c5_s[k8];
            *(float4*)&c5q[4] = *(const float4*)&c5_s[k8 + 4];
            const short8 aF = build_t(uv, vv, d, c5q);
            #pragma unroll
            for (int ct = 0; ct < 8; ct++) {
              const short8 bh = *(const short8*)&w2fH[ct][q][lane][0];
              const short8 bl = *(const short8*)&w2fL[ct][q][lane][0];
              acc[ct] = __builtin_amdgcn_mfma_f32_16x16x32_bf16(aF, bl, acc[ct], 0, 0, 0);
              acc[ct] = __builtin_amdgcn_mfma_f32_16x16x32_bf16(aF, bh, acc[ct], 0, 0, 0);
            }
          }
          #pragma unroll
          for (int ct = 0; ct < 8; ct++) {
            const float b2c = b2m_s[(ct << 4) + l15];
            #pragma unroll
            for (int q = 0; q < 4; q++)
              psum[ct] += tanh2(acc[ct][q] + b2c);
          }
        }

        // reduce over row-groups and scatter to agf (bf16 hi/lo frag layout)
        #pragma unroll
        for (int ct = 0; ct < 8; ct++) {
          float p = psum[ct];
          p += __shfl_xor(p, 16);
          p += __shfl_xor(p, 32);
          if (lane < 16) {
            const int c     = (ct << 4) + l15;
            const int plane = ((c >> 5) << 1) + (i >> 4);
            const int slot  = (i & 15) + (((c >> 3) & 3) << 4);
            const int elem  = c & 7;
            const unsigned short hb = f2bf(p);
            agfH[plane][slot][elem] = hb;
            agfL[plane][slot][elem] = f2bf(p - bf2f(hb));
          }
        }
      }
    }
    __syncthreads();   // (3) agf complete; u_s free

    // ---- Phase E1: hid = tanh2([h|aggr] @ uw1s^T + ub1*S) -> u_s.
    //      wave w: col-tile ct = w&7, row-half jt = w>>3 ----
    {
      const int ct = w & 7, jt = w >> 3;
      const int col = (ct << 4) + l15;
      const float bo = ub1[col] * TSCALE;
      floatx4 acc = {0.f,0.f,0.f,0.f};
      #pragma unroll
      for (int ks = 0; ks < 8; ks++) {
        const int idx = (((l * 8 + ct) * 8 + ks) * 64 + lane) * 8;
        const short8 bh = *(const short8*)(g_wE1_h + idx);
        const short8 bl = *(const short8*)(g_wE1_l + idx);
        short8 ah, al;
        if (ks < 4) {
          ah = *(const short8*)&hfH[ks*2+jt][lane][0];
          al = *(const short8*)&hfL[ks*2+jt][lane][0];
        } else {
          ah = *(const short8*)&agfH[(ks-4)*2+jt][lane][0];
          al = *(const short8*)&agfL[(ks-4)*2+jt][lane][0];
        }
        acc = mfma3(ah, al, bh, bl, acc);
      }
      #pragma unroll
      for (int q = 0; q < 4; q++) {
        const int r = (jt << 4) + (l4 << 2) + q;
        u_s[r][col] = tanh2(acc[q] + bo);        // u_s reused as hid32 (unscaled output)
      }
    }
    __syncthreads();   // (4) hid32 ready AND all agf/hf reads done

    if (w < 8) cvt_plane(u_s, agfH, agfL, w, lane);   // hid frags into agf
    __syncthreads();   // (5)

    // ---- Phase E2: h += tanh2(hid @ uw2s^T + ub2*S); same (ct, jt) split ----
    {
      const int ct = w & 7, jt = w >> 3;
      const int col = (ct << 4) + l15;
      const float bo = ub2[col] * TSCALE;
      floatx4 acc = {0.f,0.f,0.f,0.f};
      #pragma unroll
      for (int ks = 0; ks < 4; ks++) {
        const int idx = (((l * 8 + ct) * 4 + ks) * 64 + lane) * 8;
        const short8 bh = *(const short8*)(g_wE2_h + idx);
        const short8 bl = *(const short8*)(g_wE2_l + idx);
        const short8 ah = *(const short8*)&agfH[ks*2+jt][lane][0];
        const short8 al = *(const short8*)&agfL[ks*2+jt][lane][0];
        acc = mfma3(ah, al, bh, bl, acc);
      }
      #pragma unroll
      for (int q = 0; q < 4; q++) {
        const int r = (jt << 4) + (l4 << 2) + q;
        h32[r][col] += tanh2(acc[q] + bo);
      }
    }
    __syncthreads();   // (6) h updated

    if (l + 1 < NLAY) {
      if (w < 8) cvt_plane(h32, hfH, hfL, w, lane);
      __syncthreads();
    }
  }

  // ---------------- write out ----------------
  for (int idx = tid; idx < NN * EMB; idx += 1024)
    out[b * NN * EMB + idx] = h32[idx >> 7][idx & 127];
}

extern "C" void kernel_launch(void* const* d_in, const int* in_sizes, int n_in,
                              void* d_out, int out_size, void* d_ws, size_t ws_size,
                              hipStream_t stream) {
  const float* pos     = (const float*)d_in[0];
  const float* enc     = (const float*)d_in[1];
  const float* pos_emb = (const float*)d_in[2];
  const float* na_emb  = (const float*)d_in[3];
  const int*   T       = (const int*)d_in[4];
  // d_in[5] = num_agents (compile-time 32)
  const float* fc1_w = (const float*)d_in[6];
  const float* fc1_b = (const float*)d_in[7];
  const float* fc2_w = (const float*)d_in[8];
  const float* fc2_b = (const float*)d_in[9];
  const float* lin_w = (const float*)d_in[10];
  const float* lin_b = (const float*)d_in[11];
  const float* msg_w1 = (const float*)d_in[12];
  const float* msg_b1 = (const float*)d_in[13];
  const float* msg_w2 = (const float*)d_in[14];
  const float* msg_b2 = (const float*)d_in[15];
  const float* upd_w1 = (const float*)d_in[16];
  const float* upd_b1 = (const float*)d_in[17];
  const float* upd_w2 = (const float*)d_in[18];
  const float* upd_b2 = (const float*)d_in[19];

  wconv<<<192, 256, 0, stream>>>(msg_w1, msg_w2, upd_w1, upd_w2);
  fsd_fused<<<256, 1024, 0, stream>>>(pos, enc, pos_emb, na_emb, T,
      fc1_w, fc1_b, fc2_w, fc2_b, lin_w, lin_b,
      msg_w1, msg_b1, msg_b2, upd_b1, upd_b2,
      (float*)d_out);
}